// Round 1
// 377.484 us; speedup vs baseline: 1.0303x; 1.0303x over previous
//
#include <hip/hip_runtime.h>
#include <cmath>

#define B_ 256
#define G_ 2048
#define F_ 128
#define RNN_ 512
#define K_ 128

// ---------------------------------------------------------------------------
// Fully fused kernel: one block per batch element b, 1024 threads (16 waves).
//   Phase A: scorer_norm[f] = tanh(h_t[b]·W[:,f] + b_map[f]) / ||row||  (LDS)
//   Phase B: sc[g] = node[b][g][:]·scorer_norm  (streams 1 MB/block at BW)
//   Phase C: u64 radix-select top-128 (early exit) + rank by count
//   Phase D: log-sum-exp + policy
//   Phase E: gather + transpose + tanh-scale with register prefetch
// No workspace, no inter-kernel barriers, scores never leave LDS.
// ---------------------------------------------------------------------------
__global__ __launch_bounds__(1024) void k_fused(const float* __restrict__ node,
                                                const float* __restrict__ mask,
                                                const float* __restrict__ h_t,
                                                const float* __restrict__ W,
                                                const float* __restrict__ b_map,
                                                float* __restrict__ out,
                                                float* __restrict__ policy) {
    __shared__ __align__(16) float sc[G_];        // 8 KB scores
    __shared__ unsigned hist[2][8][256];          // 16 KB radix histograms
    __shared__ __align__(16) float tile[K_][33];  // 16.9 KB (phase A scratch + phase E tile)
    __shared__ __align__(16) float sn[F_];        // scorer_norm
    __shared__ unsigned long long win[K_];
    __shared__ float valk[K_];
    __shared__ float tanhv[K_];
    __shared__ int idxk[K_];
    __shared__ float red16[16];
    __shared__ unsigned long long prefix_sh;
    __shared__ int need_sh;
    __shared__ int done_sh;
    __shared__ int cnt;

    const int b = blockIdx.x;
    const int tid = threadIdx.x;
    const int wv = tid >> 6;   // 0..15
    const int lane = tid & 63;

    // ---- Phase A: scorer (tile LDS aliased as h[512] + wpart[8][128]) ----
    float* hsm = &tile[0][0];
    float(*wp)[F_] = (float(*)[F_])(hsm + RNN_);
    if (tid < RNN_) hsm[tid] = h_t[b * RNN_ + tid];
    if (tid == 0) { cnt = 0; done_sh = 0; }
    for (int i = tid; i < 8 * 256; i += 1024) ((unsigned*)hist[0])[i] = 0u;
    __syncthreads();
    {
        const int f = tid & 127;
        const int qu = tid >> 7;  // 0..7, 64 rows of W each
        float acc = 0.f;
        const int r0 = qu * (RNN_ / 8);
#pragma unroll 8
        for (int r = r0; r < r0 + RNN_ / 8; ++r) acc += hsm[r] * W[r * F_ + f];
        wp[qu][f] = acc;
    }
    __syncthreads();
    float tval = 0.f;
    if (tid < F_) {
        float a = b_map[tid];
#pragma unroll
        for (int q = 0; q < 8; ++q) a += wp[q][tid];
        tval = tanhf(a);
    }
    float v = tval * tval;
#pragma unroll
    for (int off = 32; off; off >>= 1) v += __shfl_xor(v, off);
    if (tid == 0) red16[0] = v;
    if (tid == 64) red16[1] = v;
    __syncthreads();
    if (tid < F_) sn[tid] = tval / sqrtf(red16[0] + red16[1]);
    __syncthreads();

    // ---- Phase B: scores. 32 half-waves, each handles 64 rows; block-wide
    // each r-step touches a contiguous 16 KB window of node[b]. ----
    {
        const int hw = tid >> 5;
        const int l32 = tid & 31;
        const float4 s4 = ((const float4*)sn)[l32];
        const float4* nb = (const float4*)(node + (size_t)b * (G_ * F_));
#pragma unroll 2
        for (int r = 0; r < 64; r += 4) {
            const float4 e0 = nb[(size_t)(((r + 0) << 5) + hw) * 32 + l32];
            const float4 e1 = nb[(size_t)(((r + 1) << 5) + hw) * 32 + l32];
            const float4 e2 = nb[(size_t)(((r + 2) << 5) + hw) * 32 + l32];
            const float4 e3 = nb[(size_t)(((r + 3) << 5) + hw) * 32 + l32];
            float p0 = e0.x * s4.x + e0.y * s4.y + e0.z * s4.z + e0.w * s4.w;
            float p1 = e1.x * s4.x + e1.y * s4.y + e1.z * s4.z + e1.w * s4.w;
            float p2 = e2.x * s4.x + e2.y * s4.y + e2.z * s4.z + e2.w * s4.w;
            float p3 = e3.x * s4.x + e3.y * s4.y + e3.z * s4.z + e3.w * s4.w;
#pragma unroll
            for (int off = 16; off; off >>= 1) {
                p0 += __shfl_xor(p0, off);
                p1 += __shfl_xor(p1, off);
                p2 += __shfl_xor(p2, off);
                p3 += __shfl_xor(p3, off);
            }
            if (l32 == 0) {
                sc[((r + 0) << 5) + hw] = p0;
                sc[((r + 1) << 5) + hw] = p1;
                sc[((r + 2) << 5) + hw] = p2;
                sc[((r + 3) << 5) + hw] = p3;
            }
        }
    }
    __syncthreads();

    // ---- Phase C: keys (+mask, coalesced float2), radix select ----
    unsigned long long kreg[2];
    float vv0, vv1;
    {
        const float2 v2 = ((const float2*)sc)[tid];
        const float2 m2 = ((const float2*)(mask + (size_t)b * G_))[tid];
        vv0 = v2.x + m2.x;
        vv1 = v2.y + m2.y;
        float2 wb;
        wb.x = vv0;
        wb.y = vv1;
        ((float2*)sc)[tid] = wb;
        unsigned u0 = __float_as_uint(vv0);
        u0 = (u0 & 0x80000000u) ? ~u0 : (u0 | 0x80000000u);
        kreg[0] = ((unsigned long long)u0 << 32) | (unsigned)(G_ - 1 - (2 * tid + 0));
        unsigned u1 = __float_as_uint(vv1);
        u1 = (u1 & 0x80000000u) ? ~u1 : (u1 | 0x80000000u);
        kreg[1] = ((unsigned long long)u1 << 32) | (unsigned)(G_ - 1 - (2 * tid + 1));
    }
    __syncthreads();

    unsigned long long prefix = 0ull;
    int need = K_;
    int round = 0;
    const int wv8 = wv & 7;
    for (int shift = 56; shift >= 0; shift -= 8, ++round) {
        unsigned(*H)[256] = hist[round & 1];
        const unsigned long long hi_mask = (shift == 56) ? 0ull : (~0ull << (shift + 8));
#pragma unroll
        for (int p = 0; p < 2; ++p) {
            const unsigned long long key = kreg[p];
            if ((key & hi_mask) == prefix)
                atomicAdd(&H[wv8][(unsigned)(key >> shift) & 255u], 1u);
        }
        __syncthreads();
        if (wv == 0) {
            const int L = lane;
            unsigned h0 = 0, h1 = 0, h2 = 0, h3 = 0;
#pragma unroll
            for (int ww = 0; ww < 8; ++ww) {
                h0 += H[ww][4 * L + 0];
                h1 += H[ww][4 * L + 1];
                h2 += H[ww][4 * L + 2];
                h3 += H[ww][4 * L + 3];
            }
            const unsigned s3 = h3, s2 = h2 + s3, s1 = h1 + s2, s0 = h0 + s1;
            unsigned S = s0;
            for (int off = 1; off < 64; off <<= 1) {
                const unsigned tt = __shfl_down(S, off);
                if (L + off < 64) S += tt;
            }
            unsigned Snext = __shfl_down(S, 1);
            if (L == 63) Snext = 0;
            const unsigned un = (unsigned)need;
            const unsigned suf0 = Snext + s0, suf1 = Snext + s1;
            const unsigned suf2 = Snext + s2, suf3 = Snext + s3, suf4 = Snext;
            int d = -1;
            unsigned sd = 0, sd1 = 0;
            if (suf0 >= un && suf1 < un) { d = 4 * L + 0; sd = suf0; sd1 = suf1; }
            else if (suf1 >= un && suf2 < un) { d = 4 * L + 1; sd = suf1; sd1 = suf2; }
            else if (suf2 >= un && suf3 < un) { d = 4 * L + 2; sd = suf2; sd1 = suf3; }
            else if (suf3 >= un && suf4 < un) { d = 4 * L + 3; sd = suf3; sd1 = suf4; }
            if (d >= 0) {
                prefix_sh = prefix | ((unsigned long long)(unsigned)d << shift);
                need_sh = need - (int)sd1;
                done_sh = (sd == un);
            }
        } else {
            unsigned* Z = (unsigned*)hist[(round + 1) & 1];
            for (int i = tid - 64; i < 8 * 256; i += 1024 - 64) Z[i] = 0u;
        }
        __syncthreads();
        prefix = prefix_sh;
        need = need_sh;
        if (done_sh) break;
    }
    const unsigned long long T = prefix;  // exactly 128 keys >= T

    // ---- compact winners (unordered), rank by count ----
#pragma unroll
    for (int p = 0; p < 2; ++p) {
        if (kreg[p] >= T) {
            const int q = atomicAdd(&cnt, 1);
            if (q < K_) win[q] = kreg[p];
        }
    }
    __syncthreads();
    if (tid < K_) {
        const unsigned long long mykey = win[tid];
        int rank = 0;
#pragma unroll 8
        for (int j = 0; j < K_; ++j) rank += (win[j] > mykey) ? 1 : 0;
        const int idx = G_ - 1 - (int)(unsigned)(mykey & 0xFFFFFFFFull);
        const float val = sc[idx];
        idxk[rank] = idx;
        valk[rank] = val;
        tanhv[rank] = tanhf(val);
    }
    __syncthreads();

    // ---- Phase D: log-sum-exp + policy (scores still live in registers) ----
    const float maxv = valk[0];
    float s = expf(vv0 - maxv) + expf(vv1 - maxv);
#pragma unroll
    for (int off = 32; off; off >>= 1) s += __shfl_xor(s, off);
    if (lane == 0) red16[wv] = s;
    __syncthreads();
    if (tid == 0) {
        float tot = 0.f;
#pragma unroll
        for (int i = 0; i < 16; ++i) tot += red16[i];
        const float lse = maxv + logf(tot);
        float sum = 0.f;
        for (int k = 0; k < K_; ++k) sum += valk[k];
        policy[b] = sum * (1.0f / K_) - lse;
    }

    // ---- Phase E: gather + transpose + scale with register prefetch ----
    const float* nbase = node + (size_t)b * (G_ * F_);
    float* ob = out + (size_t)b * (F_ * K_);
    const int k2 = tid >> 3;
    const int q8 = tid & 7;
    float4 pre = *(const float4*)(nbase + (size_t)idxk[k2] * F_ + 4 * q8);
    for (int f0 = 0; f0 < F_; f0 += 32) {
        tile[k2][4 * q8 + 0] = pre.x;
        tile[k2][4 * q8 + 1] = pre.y;
        tile[k2][4 * q8 + 2] = pre.z;
        tile[k2][4 * q8 + 3] = pre.w;
        __syncthreads();
        if (f0 + 32 < F_)  // issue next pass's loads before the stores
            pre = *(const float4*)(nbase + (size_t)idxk[k2] * F_ + (f0 + 32) + 4 * q8);
#pragma unroll
        for (int j = 0; j < 4; ++j) {
            const int e = tid + j * 1024;
            const int f = e >> 7;
            const int kk = e & 127;
            ob[(size_t)(f0 + f) * K_ + kk] = tile[kk][f] * tanhv[kk];
        }
        __syncthreads();
    }
}

extern "C" void kernel_launch(void* const* d_in, const int* in_sizes, int n_in,
                              void* d_out, int out_size, void* d_ws, size_t ws_size,
                              hipStream_t stream) {
    const float* node = (const float*)d_in[0];
    const float* mask = (const float*)d_in[1];
    const float* h_t = (const float*)d_in[2];
    const float* W = (const float*)d_in[3];
    const float* bm = (const float*)d_in[4];

    float* out = (float*)d_out;                  // [B, F, K]
    float* policy = out + (size_t)B_ * F_ * K_;  // [B]

    k_fused<<<B_, 1024, 0, stream>>>(node, mask, h_t, W, bm, out, policy);
}